// Round 10
// baseline (17064.705 us; speedup 1.0000x reference)
//
#include <hip/hip_runtime.h>
#include <math.h>

constexpr int      kLevels = 16;
constexpr unsigned kT      = 1u << 19;
constexpr int      kHidden = 64;
constexpr int      kInDim  = 32;
constexpr int      kOutDim = 16;
constexpr int      kMlpB   = 512;    // %8==0

struct LevelParams {
    float    scale[kLevels];
    unsigned res[kLevels];
    unsigned dense[kLevels];
};

typedef __attribute__((ext_vector_type(8))) short bf16x8;
typedef __attribute__((ext_vector_type(4))) float f32x4;
typedef __attribute__((ext_vector_type(2))) unsigned uint2v;

// ---- manual bf16 helpers ----
__device__ inline float bf2f(unsigned short b) {
    unsigned u = ((unsigned)b) << 16;
    return __builtin_bit_cast(float, u);
}
__device__ inline unsigned short f2bf(float f) {
    unsigned u = __builtin_bit_cast(unsigned, f);
    unsigned r = (u + 0x7fffu + ((u >> 16) & 1u)) >> 16;   // RTN-even
    return (unsigned short)r;
}
__device__ inline unsigned pack2bf(float a, float b) {
    return (unsigned)f2bf(a) | ((unsigned)f2bf(b) << 16);
}

// ---- kernel T: f32 table -> packed bf16 table in ws ----
// R9(f32 expt): conversion is NOT overhead — bf16 keeps hashed tables 2MB
// (L2-resident) and halves gather payload (f32-direct: 271->359us).
__global__ __launch_bounds__(256) void convert_table(
        const float* __restrict__ t, unsigned* __restrict__ o, int n4)
{
    int i = blockIdx.x * blockDim.x + threadIdx.x;
    if (i >= n4) return;
    float4 v = ((const float4*)t)[i];
    ((uint2*)o)[i] = make_uint2(pack2bf(v.x, v.y), pack2bf(v.z, v.w));
}

// ---- encode body (VERIFIED 271us floor math, R3/R7) ----
// R4: never nt table gathers. R6: gather pipe saturates ~16 waves/CU.
// R7/R8-fusion: level-major GRID mandatory (block lives on ONE level).
__device__ __forceinline__ void encode_body(
        const float* __restrict__ x,
        const unsigned* __restrict__ tblAll,   // [16][kT] packed bf16x2
        unsigned* __restrict__ enc,            // [16][N]  packed bf16x2
        int N, int l, int xb, const LevelParams& lp, int tid)
{
    const float    scale = lp.scale[l];
    const unsigned res   = lp.res[l];
    const bool     dense = (lp.dense[l] != 0);   // wave-uniform
    const unsigned* tbl  = tblAll + (size_t)l * kT;

    const int pBase = xb * 1024 + tid;

    float xs[4], ys[4], zs[4];
    #pragma unroll
    for (int q = 0; q < 4; ++q) {
        int p = pBase + q * 256;
        if (p >= N) p = N - 1;
        xs[q] = x[3 * p + 0];
        ys[q] = x[3 * p + 1];
        zs[q] = x[3 * p + 2];
    }

    unsigned v0[4][4], v1[4][4];
    float    wyz[4][4], wgx[4], wfx[4];

    #pragma unroll
    for (int q = 0; q < 4; ++q) {
        const float x0 = fminf(fmaxf((xs[q] + 1.0f) * 0.5f, 0.0f), 1.0f);
        const float y0 = fminf(fmaxf((ys[q] + 1.0f) * 0.5f, 0.0f), 1.0f);
        const float z0 = fminf(fmaxf((zs[q] + 1.0f) * 0.5f, 0.0f), 1.0f);

        const float posx = x0 * scale + 0.5f;
        const float posy = y0 * scale + 0.5f;
        const float posz = z0 * scale + 0.5f;
        const float fgx = floorf(posx), fgy = floorf(posy), fgz = floorf(posz);
        const float fx = posx - fgx, fy = posy - fgy, fz = posz - fgz;
        const float gy = 1.0f - fy,  gz = 1.0f - fz;
        const unsigned ix = (unsigned)fgx, iy = (unsigned)fgy, iz = (unsigned)fgz;

        wgx[q] = 1.0f - fx;
        wfx[q] = fx;

        #pragma unroll
        for (int c2 = 0; c2 < 4; ++c2) {
            const unsigned cy = iy + (c2 & 1);
            const unsigned cz = iz + (c2 >> 1);
            wyz[q][c2] = ((c2 & 1) ? fy : gy) * ((c2 >> 1) ? fz : gz);

            if (dense) {
                const unsigned base = cy * res + cz * res * res;
                const unsigned idx0 = (ix + base) & (kT - 1u);
                if ((idx0 & 1u) == 0u) {
                    const uint2v pr = *(const uint2v*)(tbl + idx0);
                    v0[q][c2] = pr.x; v1[q][c2] = pr.y;
                } else {
                    v0[q][c2] = tbl[idx0];
                    v1[q][c2] = tbl[idx0 + 1u];
                }
            } else {
                const unsigned base = (cy * 2654435761u) ^ (cz * 805459861u);
                const unsigned idx0 = (ix ^ base) & (kT - 1u);
                if ((ix & 1u) == 0u) {
                    const unsigned b = idx0 & ~1u;
                    const uint2v pr = *(const uint2v*)(tbl + b);
                    const bool sw = (idx0 & 1u) != 0u;
                    v0[q][c2] = sw ? pr.y : pr.x;
                    v1[q][c2] = sw ? pr.x : pr.y;
                } else {
                    const unsigned idx1 = ((ix + 1u) ^ base) & (kT - 1u);
                    v0[q][c2] = tbl[idx0];
                    v1[q][c2] = tbl[idx1];
                }
            }
        }
    }

    #pragma unroll
    for (int q = 0; q < 4; ++q) {
        float a0 = 0.0f, a1 = 0.0f;
        #pragma unroll
        for (int c2 = 0; c2 < 4; ++c2) {
            const float w0 = wgx[q] * wyz[q][c2];
            const float w1 = wfx[q] * wyz[q][c2];
            a0 = fmaf(bf2f((unsigned short)(v0[q][c2] & 0xffffu)), w0, a0);
            a1 = fmaf(bf2f((unsigned short)(v0[q][c2] >> 16)),     w0, a1);
            a0 = fmaf(bf2f((unsigned short)(v1[q][c2] & 0xffffu)), w1, a0);
            a1 = fmaf(bf2f((unsigned short)(v1[q][c2] >> 16)),     w1, a1);
        }
        const int p = pBase + q * 256;
        if (p < N)
            __builtin_nontemporal_store(pack2bf(a0, a1), &enc[(size_t)l * N + p]);
    }
}

// ---- mlp body (verified math; coalesced epilogue).
// SYNC=true: spin on per-1024-pt-slab counters (16 levels each) before
// reading a tile; prefetch guarded by the same readiness check.
template <bool SYNC>
__device__ __forceinline__ void mlp_body(
        const unsigned* __restrict__ enc,
        const float* __restrict__ W0, const float* __restrict__ b0,
        const float* __restrict__ W1, const float* __restrict__ b1,
        float* __restrict__ out, int N, int nTiles,
        int mbid, int nMlpWaves, unsigned* cnt)
{
    constexpr int kHStride = 72;
    __shared__ short lds_h[4][16 * kHStride];
    __shared__ float lds_o[4][16 * 16];

    const int wave = threadIdx.x >> 6;
    const int lane = threadIdx.x & 63;
    const int quad = lane >> 4;
    const int l16  = lane & 15;

    union Frag { bf16x8 v; short s[8]; unsigned u[4]; };

    Frag w0f[4];
    #pragma unroll
    for (int hb = 0; hb < 4; ++hb) {
        #pragma unroll
        for (int j = 0; j < 8; ++j) {
            const int k = quad * 8 + j;
            const int n = hb * 16 + l16;
            w0f[hb].s[j] = (short)f2bf(W0[n * kInDim + k]);
        }
    }
    Frag w1f[2];
    #pragma unroll
    for (int kb = 0; kb < 2; ++kb) {
        #pragma unroll
        for (int j = 0; j < 8; ++j) {
            const int k = kb * 32 + quad * 8 + j;
            const int n = l16;
            w1f[kb].s[j] = (short)f2bf(W1[n * kHidden + k]);
        }
    }
    float b0v[4];
    #pragma unroll
    for (int hb = 0; hb < 4; ++hb) b0v[hb] = b0[hb * 16 + l16];
    const float b1v = b1[l16];

    short* hrow = lds_h[wave];
    float* orow = lds_o[wave];

    auto loadFrag = [&](int t, Frag& f) {
        const int P = t * 16;
        int p = P + l16;
        if (p >= N) p = N - 1;
        #pragma unroll
        for (int j2 = 0; j2 < 4; ++j2)
            f.u[j2] = __builtin_nontemporal_load(
                          &enc[(size_t)(quad * 4 + j2) * N + p]);
    };
    auto ready = [&](int t) -> bool {
        return __hip_atomic_load(&cnt[t >> 6], __ATOMIC_ACQUIRE,
                                 __HIP_MEMORY_SCOPE_AGENT) >= 16u;
    };

    int t = mbid * 4 + wave;
    if (t >= nTiles) return;

    Frag af;
    bool have = false;
    if constexpr (!SYNC) { loadFrag(t, af); have = true; }

    for (; t < nTiles; t += nMlpWaves) {
        if constexpr (SYNC) {
            while (!ready(t)) __builtin_amdgcn_s_sleep(4);
        }
        if (!have) loadFrag(t, af);

        // prefetch next tile (guarded when SYNC)
        const int tn = t + nMlpWaves;
        Frag afn;
        bool haveN = false;
        if (tn < nTiles) {
            if constexpr (SYNC) {
                if (ready(tn)) { loadFrag(tn, afn); haveN = true; }
            } else {
                loadFrag(tn, afn); haveN = true;
            }
        }

        const int P = t * 16;

        f32x4 acc[4];
        #pragma unroll
        for (int hb = 0; hb < 4; ++hb) {
            acc[hb] = f32x4{b0v[hb], b0v[hb], b0v[hb], b0v[hb]};
            acc[hb] = __builtin_amdgcn_mfma_f32_16x16x32_bf16(
                          af.v, w0f[hb].v, acc[hb], 0, 0, 0);
        }

        #pragma unroll
        for (int hb = 0; hb < 4; ++hb) {
            #pragma unroll
            for (int r = 0; r < 4; ++r) {
                const float a = acc[hb][r];
                const float z = 100.0f * a;
                const float h = (z > 20.0f) ? a
                              : (__logf(1.0f + __expf(z)) * 0.01f);
                const int row = quad * 4 + r;
                const int col = hb * 16 + l16;
                hrow[row * kHStride + col] = (short)f2bf(h);
            }
        }
        bf16x8 h0 = *(const bf16x8*)&hrow[l16 * kHStride + quad * 8];
        bf16x8 h1 = *(const bf16x8*)&hrow[l16 * kHStride + 32 + quad * 8];

        f32x4 acc2 = f32x4{b1v, b1v, b1v, b1v};
        acc2 = __builtin_amdgcn_mfma_f32_16x16x32_bf16(h0, w1f[0].v, acc2, 0, 0, 0);
        acc2 = __builtin_amdgcn_mfma_f32_16x16x32_bf16(h1, w1f[1].v, acc2, 0, 0, 0);

        #pragma unroll
        for (int r = 0; r < 4; ++r)
            orow[(quad * 4 + r) * 16 + l16] = acc2[r];

        float* gbase = out + (size_t)N + (size_t)P * 15u;
        #pragma unroll
        for (int gp = 0; gp < 4; ++gp) {
            const int g = gp * 64 + lane;
            if (g < 240) {
                const int pt = g / 15;
                const int k  = g - pt * 15;
                if (P + pt < N)
                    __builtin_nontemporal_store(orow[pt * 16 + k + 1], &gbase[g]);
            }
        }
        if (lane < 16 && P + lane < N)
            __builtin_nontemporal_store(orow[lane * 16 + 0], &out[P + lane]);

        af = afn;
        have = haveN;
    }
}

// ---- R13: single-launch producer/consumer pipeline.
// R11/R12 isolated: overlap works (mixed stage 90 < serial 104) but the
// chunked-launch ladder loses it to fill/drain + per-chunk table refetch.
// This kernel removes launch boundaries: 512 mlp blocks dispatch FIRST
// (resident, persistent, spin on slab counters), encode blocks follow,
// xb-INTERLEAVED: ebid -> xb=ebid>>4, s=ebid&15; s<8 => pinned level 8+s
// (XCD s), s>=8 => level (s-8+xb)&7 rotating across XCDs (R5 behavior).
// Encode block signals cnt[xb] via threadfence+atomicAdd after stores;
// slab ready at cnt==16. Encode never waits => no deadlock; mlp holds
// only 512 of ~2000 block slots => encode always progresses.
__global__ __launch_bounds__(256) void stage_pipeline(
        const float* __restrict__ x,
        const unsigned* __restrict__ tblAll,
        unsigned* __restrict__ enc,
        const float* __restrict__ W0, const float* __restrict__ b0,
        const float* __restrict__ W1, const float* __restrict__ b1,
        float* __restrict__ out,
        int N, int nxb, int nTiles, unsigned* cnt, LevelParams lp)
{
    if ((int)blockIdx.x < kMlpB) {
        mlp_body<true>(enc, W0, b0, W1, b1, out, N, nTiles,
                       blockIdx.x, kMlpB * 4, cnt);
    } else {
        const int ebid = blockIdx.x - kMlpB;
        const int xb = ebid >> 4;
        const int s  = ebid & 15;
        const int l  = (s < 8) ? (8 + s) : (((s - 8) + xb) & 7);
        encode_body(x, tblAll, enc, N, l, xb, lp, threadIdx.x);
        __threadfence();
        __syncthreads();
        if (threadIdx.x == 0) atomicAdd(&cnt[xb], 1u);
    }
}

// ---- R7 fallback pair (435us verified) for ws without counter slack ----
__global__ __launch_bounds__(256) void encode_level(
        const float* __restrict__ x,
        const unsigned* __restrict__ tblAll,
        unsigned* __restrict__ enc,
        int N, int nxb, LevelParams lp)
{
    int l, xb;
    const int pinnedBlocks = 8 * nxb;
    if ((int)blockIdx.x < pinnedBlocks) {
        l  = 8 + (blockIdx.x & 7);
        xb = blockIdx.x >> 3;
    } else {
        const int r = blockIdx.x - pinnedBlocks;
        l  = r / nxb;
        xb = r - l * nxb;
    }
    encode_body(x, tblAll, enc, N, l, xb, lp, threadIdx.x);
}

__global__ __launch_bounds__(256) void mlp_mfma(
        const unsigned* __restrict__ enc,
        const float* __restrict__ W0, const float* __restrict__ b0,
        const float* __restrict__ W1, const float* __restrict__ b1,
        float* __restrict__ out, int N, int nTiles)
{
    mlp_body<false>(enc, W0, b0, W1, b1, out, N, nTiles,
                    blockIdx.x, gridDim.x * 4, nullptr);
}

// ---- fallback: fused scalar kernel (used only if ws too small) ----
__global__ __launch_bounds__(256) void sdf_fused(
        const float* __restrict__ x, const float* __restrict__ table,
        const float* __restrict__ W0, const float* __restrict__ b0,
        const float* __restrict__ W1, const float* __restrict__ b1,
        float* __restrict__ out, int N, LevelParams lp)
{
    const int gid = blockIdx.x * blockDim.x + threadIdx.x;
    if (gid >= N) return;
    const float x0 = fminf(fmaxf((x[3 * gid + 0] + 1.0f) * 0.5f, 0.0f), 1.0f);
    const float y0 = fminf(fmaxf((x[3 * gid + 1] + 1.0f) * 0.5f, 0.0f), 1.0f);
    const float z0 = fminf(fmaxf((x[3 * gid + 2] + 1.0f) * 0.5f, 0.0f), 1.0f);
    float enc[kInDim];
    #pragma unroll
    for (int l = 0; l < kLevels; ++l) {
        const float scale = lp.scale[l];
        const unsigned res = lp.res[l];
        const bool dense = (lp.dense[l] != 0);
        const float posx = x0 * scale + 0.5f, posy = y0 * scale + 0.5f, posz = z0 * scale + 0.5f;
        const float fgx = floorf(posx), fgy = floorf(posy), fgz = floorf(posz);
        const float fx = posx - fgx, fy = posy - fgy, fz = posz - fgz;
        const float gx = 1.0f - fx, gy = 1.0f - fy, gz = 1.0f - fz;
        const unsigned ix = (unsigned)fgx, iy = (unsigned)fgy, iz = (unsigned)fgz;
        const float* tbl = table + (size_t)l * kT * 2u;
        float a0 = 0.0f, a1 = 0.0f;
        #pragma unroll
        for (int c = 0; c < 8; ++c) {
            const unsigned cx = ix + (c & 1), cy = iy + ((c >> 1) & 1), cz = iz + ((c >> 2) & 1);
            unsigned idx = dense ? (cx + cy * res + cz * res * res)
                                 : (cx ^ (cy * 2654435761u) ^ (cz * 805459861u));
            idx &= (kT - 1u);
            const float2 tv = *(const float2*)(tbl + 2u * idx);
            const float w = ((c & 1) ? fx : gx) * (((c >> 1) & 1) ? fy : gy) * (((c >> 2) & 1) ? fz : gz);
            a0 = fmaf(tv.x, w, a0); a1 = fmaf(tv.y, w, a1);
        }
        enc[2 * l] = a0; enc[2 * l + 1] = a1;
    }
    float acc[kOutDim];
    #pragma unroll
    for (int k = 0; k < kOutDim; ++k) acc[k] = b1[k];
    #pragma unroll 2
    for (int j = 0; j < kHidden; ++j) {
        float a = b0[j];
        #pragma unroll
        for (int i = 0; i < kInDim; ++i) a = fmaf(enc[i], W0[j * kInDim + i], a);
        const float z = 100.0f * a;
        const float h = (z > 20.0f) ? a : (__logf(1.0f + __expf(z)) * 0.01f);
        #pragma unroll
        for (int k = 0; k < kOutDim; ++k) acc[k] = fmaf(h, W1[k * kHidden + j], acc[k]);
    }
    out[gid] = acc[0];
    #pragma unroll
    for (int k = 0; k < 15; ++k) out[(size_t)N + (size_t)gid * 15u + k] = acc[k + 1];
}

extern "C" void kernel_launch(void* const* d_in, const int* in_sizes, int n_in,
                              void* d_out, int out_size, void* d_ws, size_t ws_size,
                              hipStream_t stream) {
    const float* x     = (const float*)d_in[0];
    const float* table = (const float*)d_in[1];
    const float* W0    = (const float*)d_in[2];
    const float* b0    = (const float*)d_in[3];
    const float* W1    = (const float*)d_in[4];
    const float* b1    = (const float*)d_in[5];
    float* out = (float*)d_out;
    const int N = in_sizes[0] / 3;

    LevelParams lp;
    const double s = exp2(7.0 / 15.0);
    for (int l = 0; l < kLevels; ++l) {
        const double sc = 16.0 * pow(s, (double)l) - 1.0;
        lp.scale[l] = (float)sc;
        const unsigned res = (unsigned)ceil(sc) + 1u;
        lp.res[l] = res;
        lp.dense[l] =
            ((unsigned long long)res * res * res <= (unsigned long long)kT) ? 1u : 0u;
    }

    const size_t tbl_bytes = (size_t)kLevels * kT * 4u;              // 32 MB
    const size_t enc_bytes = (size_t)kLevels * (size_t)N * 4u;       // 64 MB
    const int nxb = (N + 1023) / 1024;
    const int nTiles = (N + 15) / 16;
    const size_t cnt_bytes = ((size_t)nxb * 4u + 255u) & ~(size_t)255u;

    if (ws_size >= tbl_bytes + enc_bytes + cnt_bytes) {
        // ---- R13 pipeline path ----
        unsigned* tbl_bf = (unsigned*)d_ws;
        unsigned* enc    = (unsigned*)((char*)d_ws + tbl_bytes);
        unsigned* cnt    = (unsigned*)((char*)d_ws + tbl_bytes + enc_bytes);

        const int n4 = (int)(kLevels * kT * 2u / 4u);
        hipLaunchKernelGGL(convert_table, dim3((n4 + 255) / 256), dim3(256), 0, stream,
                           table, tbl_bf, n4);
        hipMemsetAsync(cnt, 0, (size_t)nxb * 4u, stream);

        hipLaunchKernelGGL(stage_pipeline, dim3(kMlpB + 16 * nxb), dim3(256), 0, stream,
                           x, tbl_bf, enc, W0, b0, W1, b1, out,
                           N, nxb, nTiles, cnt, lp);
    } else if (ws_size >= tbl_bytes + enc_bytes) {
        // ---- R7 verified split path (435us) ----
        unsigned* tbl_bf = (unsigned*)d_ws;
        unsigned* enc    = (unsigned*)((char*)d_ws + tbl_bytes);

        const int n4 = (int)(kLevels * kT * 2u / 4u);
        hipLaunchKernelGGL(convert_table, dim3((n4 + 255) / 256), dim3(256), 0, stream,
                           table, tbl_bf, n4);
        hipLaunchKernelGGL(encode_level, dim3(16 * nxb), dim3(256), 0, stream,
                           x, tbl_bf, enc, N, nxb, lp);
        hipLaunchKernelGGL(mlp_mfma, dim3(2048), dim3(256), 0, stream,
                           enc, W0, b0, W1, b1, out, N, nTiles);
    } else {
        hipLaunchKernelGGL(sdf_fused, dim3((N + 255) / 256), dim3(256), 0, stream,
                           x, table, W0, b0, W1, b1, out, N, lp);
    }
}

// Round 12
// 475.446 us; speedup vs baseline: 35.8920x; 35.8920x over previous
//
#include <hip/hip_runtime.h>
#include <math.h>

constexpr int      kLevels = 16;
constexpr unsigned kT      = 1u << 19;
constexpr int      kHidden = 64;
constexpr int      kInDim  = 32;
constexpr int      kOutDim = 16;

struct LevelParams {
    float    scale[kLevels];
    unsigned res[kLevels];
    unsigned dense[kLevels];
};

typedef __attribute__((ext_vector_type(8))) short bf16x8;
typedef __attribute__((ext_vector_type(4))) float f32x4;
typedef __attribute__((ext_vector_type(2))) unsigned uint2v;

// ---- manual bf16 helpers ----
__device__ inline float bf2f(unsigned short b) {
    unsigned u = ((unsigned)b) << 16;
    return __builtin_bit_cast(float, u);
}
__device__ inline unsigned short f2bf(float f) {
    unsigned u = __builtin_bit_cast(unsigned, f);
    unsigned r = (u + 0x7fffu + ((u >> 16) & 1u)) >> 16;   // RTN-even
    return (unsigned short)r;
}
__device__ inline unsigned pack2bf(float a, float b) {
    return (unsigned)f2bf(a) | ((unsigned)f2bf(b) << 16);
}

// ---- kernel T: f32 table -> packed bf16 table in ws ----
// bf16 tables are mandatory: 2MB/level stays L2-resident under pinning
// and halves gather payload (f32-direct: encode 271->359us).
__global__ __launch_bounds__(256) void convert_table(
        const float* __restrict__ t, unsigned* __restrict__ o, int n4)
{
    int i = blockIdx.x * blockDim.x + threadIdx.x;
    if (i >= n4) return;
    float4 v = ((const float4*)t)[i];
    ((uint2*)o)[i] = make_uint2(pack2bf(v.x, v.y), pack2bf(v.z, v.w));
}

// ---- kernel A: level-major encode (VERIFIED 271us floor config).
// Laws learned (do not violate):
//  - never nt table gathers (R4: 2x regression)
//  - levels 8..15 XCD-pinned via (bid&7), levels 0..7 spread (R5)
//  - gather pipe saturates ~16 waves/CU; 271us is the empirical floor
//    (cache tier, MLP-width, occupancy attacks all null)
//  - CONCURRENT blocks must share ONE level: any mapping that mixes
//    levels among co-resident blocks refetches tables (R7-fusion 2.2GB,
//    R8-fusion 1.6GB, R10-interleave 1.1GB)
//  - cross-stage pipelining dead: chunked ladder loses to fill/drain
//    (R8/R9), intra-launch spin+fence catastrophic (R10: 17ms)
__global__ __launch_bounds__(256) void encode_level(
        const float* __restrict__ x,
        const unsigned* __restrict__ tblAll,   // [16][kT] packed bf16x2
        unsigned* __restrict__ enc,            // [16][N]  packed bf16x2
        int N, int nxb, LevelParams lp)
{
    const int bid = blockIdx.x;
    const int tid = threadIdx.x;

    int l, xb;
    const int pinnedBlocks = 8 * nxb;
    if (bid < pinnedBlocks) {
        l  = 8 + (bid & 7);
        xb = bid >> 3;
    } else {
        const int r = bid - pinnedBlocks;
        l  = r / nxb;
        xb = r - l * nxb;
    }

    const float    scale = lp.scale[l];
    const unsigned res   = lp.res[l];
    const bool     dense = (lp.dense[l] != 0);   // wave-uniform
    const unsigned* tbl  = tblAll + (size_t)l * kT;

    const int pBase = xb * 1024 + tid;

    float xs[4], ys[4], zs[4];
    #pragma unroll
    for (int q = 0; q < 4; ++q) {
        int p = pBase + q * 256;
        if (p >= N) p = N - 1;
        xs[q] = x[3 * p + 0];
        ys[q] = x[3 * p + 1];
        zs[q] = x[3 * p + 2];
    }

    unsigned v0[4][4], v1[4][4];
    float    wyz[4][4], wgx[4], wfx[4];

    #pragma unroll
    for (int q = 0; q < 4; ++q) {
        const float x0 = fminf(fmaxf((xs[q] + 1.0f) * 0.5f, 0.0f), 1.0f);
        const float y0 = fminf(fmaxf((ys[q] + 1.0f) * 0.5f, 0.0f), 1.0f);
        const float z0 = fminf(fmaxf((zs[q] + 1.0f) * 0.5f, 0.0f), 1.0f);

        const float posx = x0 * scale + 0.5f;
        const float posy = y0 * scale + 0.5f;
        const float posz = z0 * scale + 0.5f;
        const float fgx = floorf(posx), fgy = floorf(posy), fgz = floorf(posz);
        const float fx = posx - fgx, fy = posy - fgy, fz = posz - fgz;
        const float gy = 1.0f - fy,  gz = 1.0f - fz;
        const unsigned ix = (unsigned)fgx, iy = (unsigned)fgy, iz = (unsigned)fgz;

        wgx[q] = 1.0f - fx;
        wfx[q] = fx;

        #pragma unroll
        for (int c2 = 0; c2 < 4; ++c2) {
            const unsigned cy = iy + (c2 & 1);
            const unsigned cz = iz + (c2 >> 1);
            wyz[q][c2] = ((c2 & 1) ? fy : gy) * ((c2 >> 1) ? fz : gz);

            if (dense) {
                const unsigned base = cy * res + cz * res * res;
                const unsigned idx0 = (ix + base) & (kT - 1u);
                if ((idx0 & 1u) == 0u) {
                    const uint2v pr = *(const uint2v*)(tbl + idx0);
                    v0[q][c2] = pr.x; v1[q][c2] = pr.y;
                } else {
                    v0[q][c2] = tbl[idx0];
                    v1[q][c2] = tbl[idx0 + 1u];
                }
            } else {
                const unsigned base = (cy * 2654435761u) ^ (cz * 805459861u);
                const unsigned idx0 = (ix ^ base) & (kT - 1u);
                if ((ix & 1u) == 0u) {
                    const unsigned b = idx0 & ~1u;
                    const uint2v pr = *(const uint2v*)(tbl + b);
                    const bool sw = (idx0 & 1u) != 0u;
                    v0[q][c2] = sw ? pr.y : pr.x;
                    v1[q][c2] = sw ? pr.x : pr.y;
                } else {
                    const unsigned idx1 = ((ix + 1u) ^ base) & (kT - 1u);
                    v0[q][c2] = tbl[idx0];
                    v1[q][c2] = tbl[idx1];
                }
            }
        }
    }

    #pragma unroll
    for (int q = 0; q < 4; ++q) {
        float a0 = 0.0f, a1 = 0.0f;
        #pragma unroll
        for (int c2 = 0; c2 < 4; ++c2) {
            const float w0 = wgx[q] * wyz[q][c2];
            const float w1 = wfx[q] * wyz[q][c2];
            a0 = fmaf(bf2f((unsigned short)(v0[q][c2] & 0xffffu)), w0, a0);
            a1 = fmaf(bf2f((unsigned short)(v0[q][c2] >> 16)),     w0, a1);
            a0 = fmaf(bf2f((unsigned short)(v1[q][c2] & 0xffffu)), w1, a0);
            a1 = fmaf(bf2f((unsigned short)(v1[q][c2] >> 16)),     w1, a1);
        }
        const int p = pBase + q * 256;
        if (p < N)
            __builtin_nontemporal_store(pack2bf(a0, a1), &enc[(size_t)l * N + p]);
    }
}

// ---- kernel B: MFMA MLP, ONE TILE PER WAVE (R14).
// R8/R9 datum: mlp throughput identical at 512 vs 2048 blocks => bound
// by a per-wave serial chain (loop-carried enc-load latency, ~900cy HBM
// because enc is nt), not by resources. Fix: remove the loop entirely —
// grid = nTiles/4 blocks, each wave owns ONE tile, issues its 4 enc
// loads at launch, computes, stores, exits. TLP across thousands of
// short waves hides all latency (encode proves the dispatcher streams
// 16384 blocks at full rate). Weights are L1-broadcast (12KB, resident).
__global__ __launch_bounds__(256) void mlp_mfma(
        const unsigned* __restrict__ enc,      // [16][N] packed bf16x2
        const float* __restrict__ W0,
        const float* __restrict__ b0,
        const float* __restrict__ W1,
        const float* __restrict__ b1,
        float* __restrict__ out, int N, int nTiles)
{
    constexpr int kHStride = 72;
    __shared__ short lds_h[4][16 * kHStride];
    __shared__ float lds_o[4][16 * 16];

    const int wave = threadIdx.x >> 6;
    const int lane = threadIdx.x & 63;
    const int quad = lane >> 4;
    const int l16  = lane & 15;

    union Frag { bf16x8 v; short s[8]; unsigned u[4]; };

    const int t = blockIdx.x * 4 + wave;
    if (t >= nTiles) return;

    // ---- issue enc loads FIRST (the long-latency path) ----
    const int P = t * 16;
    int p = P + l16;
    if (p >= N) p = N - 1;
    Frag af;
    #pragma unroll
    for (int j2 = 0; j2 < 4; ++j2)
        af.u[j2] = __builtin_nontemporal_load(
                       &enc[(size_t)(quad * 4 + j2) * N + p]);

    // ---- weight fragments (L1-broadcast; overlaps enc latency) ----
    Frag w0f[4];
    #pragma unroll
    for (int hb = 0; hb < 4; ++hb) {
        #pragma unroll
        for (int j = 0; j < 8; ++j) {
            const int k = quad * 8 + j;
            const int n = hb * 16 + l16;
            w0f[hb].s[j] = (short)f2bf(W0[n * kInDim + k]);
        }
    }
    Frag w1f[2];
    #pragma unroll
    for (int kb = 0; kb < 2; ++kb) {
        #pragma unroll
        for (int j = 0; j < 8; ++j) {
            const int k = kb * 32 + quad * 8 + j;
            const int n = l16;
            w1f[kb].s[j] = (short)f2bf(W1[n * kHidden + k]);
        }
    }
    float b0v[4];
    #pragma unroll
    for (int hb = 0; hb < 4; ++hb) b0v[hb] = b0[hb * 16 + l16];
    const float b1v = b1[l16];

    short* hrow = lds_h[wave];
    float* orow = lds_o[wave];

    f32x4 acc[4];
    #pragma unroll
    for (int hb = 0; hb < 4; ++hb) {
        acc[hb] = f32x4{b0v[hb], b0v[hb], b0v[hb], b0v[hb]};
        acc[hb] = __builtin_amdgcn_mfma_f32_16x16x32_bf16(
                      af.v, w0f[hb].v, acc[hb], 0, 0, 0);
    }

    #pragma unroll
    for (int hb = 0; hb < 4; ++hb) {
        #pragma unroll
        for (int r = 0; r < 4; ++r) {
            const float a = acc[hb][r];
            const float z = 100.0f * a;
            const float h = (z > 20.0f) ? a
                          : (__logf(1.0f + __expf(z)) * 0.01f);
            const int row = quad * 4 + r;
            const int col = hb * 16 + l16;
            hrow[row * kHStride + col] = (short)f2bf(h);
        }
    }
    bf16x8 h0 = *(const bf16x8*)&hrow[l16 * kHStride + quad * 8];
    bf16x8 h1 = *(const bf16x8*)&hrow[l16 * kHStride + 32 + quad * 8];

    f32x4 acc2 = f32x4{b1v, b1v, b1v, b1v};
    acc2 = __builtin_amdgcn_mfma_f32_16x16x32_bf16(h0, w1f[0].v, acc2, 0, 0, 0);
    acc2 = __builtin_amdgcn_mfma_f32_16x16x32_bf16(h1, w1f[1].v, acc2, 0, 0, 0);

    // ---- coalesced epilogue (R7-verified, same absmax) ----
    #pragma unroll
    for (int r = 0; r < 4; ++r)
        orow[(quad * 4 + r) * 16 + l16] = acc2[r];

    float* gbase = out + (size_t)N + (size_t)P * 15u;
    #pragma unroll
    for (int gp = 0; gp < 4; ++gp) {
        const int g = gp * 64 + lane;
        if (g < 240) {
            const int pt = g / 15;
            const int k  = g - pt * 15;
            if (P + pt < N)
                __builtin_nontemporal_store(orow[pt * 16 + k + 1], &gbase[g]);
        }
    }
    if (lane < 16 && P + lane < N)
        __builtin_nontemporal_store(orow[lane * 16 + 0], &out[P + lane]);
}

// ---- fallback: fused scalar kernel (used only if ws too small) ----
__global__ __launch_bounds__(256) void sdf_fused(
        const float* __restrict__ x, const float* __restrict__ table,
        const float* __restrict__ W0, const float* __restrict__ b0,
        const float* __restrict__ W1, const float* __restrict__ b1,
        float* __restrict__ out, int N, LevelParams lp)
{
    const int gid = blockIdx.x * blockDim.x + threadIdx.x;
    if (gid >= N) return;
    const float x0 = fminf(fmaxf((x[3 * gid + 0] + 1.0f) * 0.5f, 0.0f), 1.0f);
    const float y0 = fminf(fmaxf((x[3 * gid + 1] + 1.0f) * 0.5f, 0.0f), 1.0f);
    const float z0 = fminf(fmaxf((x[3 * gid + 2] + 1.0f) * 0.5f, 0.0f), 1.0f);
    float enc[kInDim];
    #pragma unroll
    for (int l = 0; l < kLevels; ++l) {
        const float scale = lp.scale[l];
        const unsigned res = lp.res[l];
        const bool dense = (lp.dense[l] != 0);
        const float posx = x0 * scale + 0.5f, posy = y0 * scale + 0.5f, posz = z0 * scale + 0.5f;
        const float fgx = floorf(posx), fgy = floorf(posy), fgz = floorf(posz);
        const float fx = posx - fgx, fy = posy - fgy, fz = posz - fgz;
        const float gx = 1.0f - fx, gy = 1.0f - fy, gz = 1.0f - fz;
        const unsigned ix = (unsigned)fgx, iy = (unsigned)fgy, iz = (unsigned)fgz;
        const float* tbl = table + (size_t)l * kT * 2u;
        float a0 = 0.0f, a1 = 0.0f;
        #pragma unroll
        for (int c = 0; c < 8; ++c) {
            const unsigned cx = ix + (c & 1), cy = iy + ((c >> 1) & 1), cz = iz + ((c >> 2) & 1);
            unsigned idx = dense ? (cx + cy * res + cz * res * res)
                                 : (cx ^ (cy * 2654435761u) ^ (cz * 805459861u));
            idx &= (kT - 1u);
            const float2 tv = *(const float2*)(tbl + 2u * idx);
            const float w = ((c & 1) ? fx : gx) * (((c >> 1) & 1) ? fy : gy) * (((c >> 2) & 1) ? fz : gz);
            a0 = fmaf(tv.x, w, a0); a1 = fmaf(tv.y, w, a1);
        }
        enc[2 * l] = a0; enc[2 * l + 1] = a1;
    }
    float acc[kOutDim];
    #pragma unroll
    for (int k = 0; k < kOutDim; ++k) acc[k] = b1[k];
    #pragma unroll 2
    for (int j = 0; j < kHidden; ++j) {
        float a = b0[j];
        #pragma unroll
        for (int i = 0; i < kInDim; ++i) a = fmaf(enc[i], W0[j * kInDim + i], a);
        const float z = 100.0f * a;
        const float h = (z > 20.0f) ? a : (__logf(1.0f + __expf(z)) * 0.01f);
        #pragma unroll
        for (int k = 0; k < kOutDim; ++k) acc[k] = fmaf(h, W1[k * kHidden + j], acc[k]);
    }
    out[gid] = acc[0];
    #pragma unroll
    for (int k = 0; k < 15; ++k) out[(size_t)N + (size_t)gid * 15u + k] = acc[k + 1];
}

extern "C" void kernel_launch(void* const* d_in, const int* in_sizes, int n_in,
                              void* d_out, int out_size, void* d_ws, size_t ws_size,
                              hipStream_t stream) {
    const float* x     = (const float*)d_in[0];
    const float* table = (const float*)d_in[1];
    const float* W0    = (const float*)d_in[2];
    const float* b0    = (const float*)d_in[3];
    const float* W1    = (const float*)d_in[4];
    const float* b1    = (const float*)d_in[5];
    float* out = (float*)d_out;
    const int N = in_sizes[0] / 3;

    LevelParams lp;
    const double s = exp2(7.0 / 15.0);
    for (int l = 0; l < kLevels; ++l) {
        const double sc = 16.0 * pow(s, (double)l) - 1.0;
        lp.scale[l] = (float)sc;
        const unsigned res = (unsigned)ceil(sc) + 1u;
        lp.res[l] = res;
        lp.dense[l] =
            ((unsigned long long)res * res * res <= (unsigned long long)kT) ? 1u : 0u;
    }

    const size_t tbl_bytes = (size_t)kLevels * kT * 4u;              // 32 MB packed bf16x2
    const size_t enc_bytes = (size_t)kLevels * (size_t)N * 4u;       // 64 MB packed bf16x2

    if (ws_size >= tbl_bytes + enc_bytes) {
        unsigned* tbl_bf = (unsigned*)d_ws;
        unsigned* enc    = (unsigned*)((char*)d_ws + tbl_bytes);

        const int n4 = (int)(kLevels * kT * 2u / 4u);
        hipLaunchKernelGGL(convert_table, dim3((n4 + 255) / 256), dim3(256), 0, stream,
                           table, tbl_bf, n4);

        const int nxb = (N + 1023) / 1024;
        hipLaunchKernelGGL(encode_level, dim3(16 * nxb), dim3(256), 0, stream,
                           x, tbl_bf, enc, N, nxb, lp);

        const int nTiles = (N + 15) / 16;
        hipLaunchKernelGGL(mlp_mfma, dim3((nTiles + 3) / 4), dim3(256), 0, stream,
                           enc, W0, b0, W1, b1, out, N, nTiles);
    } else {
        hipLaunchKernelGGL(sdf_fused, dim3((N + 255) / 256), dim3(256), 0, stream,
                           x, table, W0, b0, W1, b1, out, N, lp);
    }
}